// Round 6
// baseline (680.806 us; speedup 1.0000x reference)
//
#include <hip/hip_runtime.h>
#include <cstdint>
#include <cstddef>

typedef unsigned int u32;
typedef unsigned long long u64;

#define A_      15
#define N_      16
#define HW_     16384      /* 128*128 */
#define NUMEL_  245760     /* A_*HW_ */
#define PRE_    2000
#define POST_   1000
#define CAP_    4096
#define NBIN_   8192
#define NJOB_   32
#define NEG_    (-1000000000.0f)
#define CNTSTRIDE_ 16      /* one 64B line per job counter */
#define MROWS_  2048       /* padded row count in transposed mask */

// ---------------- workspace layout (bytes) ----------------
#define HIST_OFF  ((size_t)0)                         /* 32*8192*4 = 1048576 */
#define CNT_OFF   ((size_t)1048576)                   /* 32*16*4 = 2048 (padded) */
#define TBIN_OFF  ((size_t)1050624)                   /* 32*4 -> pad 128 */
#define CAND_OFF  ((size_t)1050752)                   /* 32*4096*8 = 1048576 */
#define TOPK_OFF  ((size_t)2099328)                   /* 32*2048*8 = 524288 */
#define PROP_OFF  ((size_t)2623616)                   /* 32*2000*16 = 1024000 */
#define SCOR_OFF  ((size_t)3647616)                   /* 32*2000*4 = 256000 */
#define VALD_OFF  ((size_t)3903616)                   /* 32*2000*4 = 256000 */
#define DMAT_OFF  ((size_t)4159616)                   /* 32*32*64*8 = 524288 */
#define MASK_OFF  ((size_t)4683904)                   /* transposed: 32*32*2048*8 = 16777216 */
/* total ~21.5 MB */

__device__ __forceinline__ float sigmoid_f(float x) {
#pragma clang fp contract(off)
    return 1.0f / (1.0f + expf(-x));
}

// ---- histogram of sigmoid float bits >> 17 (8192 bins), per job ----
__global__ void k_hist(const float* __restrict__ objL, const float* __restrict__ objR,
                       u32* __restrict__ hist) {
    __shared__ u32 h[NBIN_];
    int tid = threadIdx.x;
    for (int b = tid; b < NBIN_; b += 256) h[b] = 0;
    __syncthreads();
    int job = blockIdx.y;
    const float* obj = (job >= 16 ? objR : objL) + (size_t)(job & 15) * NUMEL_;
    int base = blockIdx.x * 15360;
    for (int it = 0; it < 60; ++it) {
        int e = base + it * 256 + tid;
        float s = sigmoid_f(obj[e]);
        u32 bin = __float_as_uint(s) >> 17;   // s in [0,1] -> bin <= 8128
        atomicAdd(&h[bin], 1u);
    }
    __syncthreads();
    u32* gh = hist + (size_t)job * NBIN_;
    for (int b = tid; b < NBIN_; b += 256) {
        u32 c = h[b];
        if (c) atomicAdd(&gh[b], c);
    }
}

// ---- find threshold bin T: smallest-score bin s.t. count(bin >= T) >= PRE_ ----
__global__ void k_thresh(const u32* __restrict__ hist, u32* __restrict__ tbin) {
    __shared__ u32 part[256];
    int job = blockIdx.x, tid = threadIdx.x;
    const u32* gh = hist + (size_t)job * NBIN_;
    u32 sum = 0;
    for (int b = 0; b < 32; ++b) sum += gh[tid * 32 + b];
    part[tid] = sum;
    __syncthreads();
    if (tid == 0) {
        u32 suffix = 0; int T = 0;
        for (int t = 255; t >= 0; --t) {
            if (suffix + part[t] >= PRE_) {
                for (int b = t * 32 + 31; b >= t * 32; --b) {
                    suffix += gh[b];
                    if (suffix >= PRE_) { T = b; break; }
                }
                break;
            }
            suffix += part[t];
        }
        tbin[job] = (u32)T;
    }
}

// ---- compact candidates: block-aggregated reservation (1 global atomic/block) ----
__global__ void k_compact(const float* __restrict__ objL, const float* __restrict__ objR,
                          const u32* __restrict__ tbin, u32* __restrict__ candCnt,
                          u64* __restrict__ cand) {
    __shared__ u32 lrank;
    __shared__ u32 lbase;
    int tid = threadIdx.x;
    int job = blockIdx.y;
    const float* obj = (job >= 16 ? objR : objL) + (size_t)(job & 15) * NUMEL_;
    u32 T = tbin[job];
    int base = blockIdx.x * 3840;
    if (tid == 0) lrank = 0;
    __syncthreads();
    u32 keys[15];
    u32 mymask = 0;
#pragma unroll
    for (int it = 0; it < 15; ++it) {
        int e = base + it * 256 + tid;
        float s = sigmoid_f(obj[e]);
        u32 bits = __float_as_uint(s);
        keys[it] = bits;
        if ((bits >> 17) >= T) mymask |= (1u << it);
    }
    int mycnt = __popc(mymask);
    u32 myoff = 0;
    if (mycnt) myoff = atomicAdd(&lrank, (u32)mycnt);
    __syncthreads();
    if (tid == 0) lbase = atomicAdd(&candCnt[job * CNTSTRIDE_], lrank);
    __syncthreads();
    u32 off = lbase + myoff;
    u64* cj = cand + (size_t)job * CAP_;
#pragma unroll
    for (int it = 0; it < 15; ++it) {
        if (mymask & (1u << it)) {
            int e = base + it * 256 + tid;
            // e = a*HW + hw ; score index i = hw*A + a
            u32 i = (u32)((e & (HW_ - 1)) * A_ + (e >> 14));
            if (off < CAP_) cj[off] = ((u64)keys[it] << 32) | (u64)(~i);
            off++;
        }
    }
}

// ---- per-job bitonic sort (descending) of candidate keys; emit top 2000 ----
__global__ __launch_bounds__(1024) void k_sort(const u32* __restrict__ candCnt,
                                               const u64* __restrict__ cand,
                                               u64* __restrict__ topk) {
    __shared__ u64 a[CAP_];
    int tid = threadIdx.x, job = blockIdx.x;
    u32 cnt = candCnt[job * CNTSTRIDE_]; if (cnt > CAP_) cnt = CAP_;
    const u64* c = cand + (size_t)job * CAP_;
    for (int i = tid; i < CAP_; i += 1024) a[i] = (i < (int)cnt) ? c[i] : 0ull;
    __syncthreads();
    for (int k = 2; k <= CAP_; k <<= 1) {
        for (int j = k >> 1; j > 0; j >>= 1) {
            for (int i = tid; i < CAP_; i += 1024) {
                int ixj = i ^ j;
                if (ixj > i) {
                    u64 x = a[i], y = a[ixj];
                    bool up = (i & k) == 0;
                    if (up ? (x < y) : (x > y)) { a[i] = y; a[ixj] = x; }
                }
            }
            __syncthreads();
        }
    }
    u64* t = topk + (size_t)job * 2048;
    for (int i = tid; i < PRE_; i += 1024) t[i] = a[i];
}

// ---- decode top-2000 boxes, clip, min-size validity ----
__global__ void k_decode(const float* __restrict__ anchL, const float* __restrict__ anchR,
                         const float* __restrict__ bregL, const float* __restrict__ bregR,
                         const u64* __restrict__ topk, float4* __restrict__ props,
                         float* __restrict__ pscore, u32* __restrict__ pvalid) {
#pragma clang fp contract(off)
    int k = blockIdx.x * 256 + threadIdx.x;
    if (k >= PRE_) return;
    int job = blockIdx.y;
    int n = job & 15;
    const float* anch = (job >= 16 ? anchR : anchL);
    const float* breg = (job >= 16 ? bregR : bregL);
    u64 key = topk[(size_t)job * 2048 + k];
    u32 i = ~(u32)key;
    float score = __uint_as_float((u32)(key >> 32));
    int a  = (int)(i % 15u);
    int hw = (int)(i / 15u);
    const float* ap = anch + ((size_t)n * NUMEL_ + i) * 4;
    float x1 = ap[0], y1 = ap[1], x2 = ap[2], y2 = ap[3];
    const float* bp = breg + (size_t)n * (A_ * 4) * HW_ + (size_t)(a * 4) * HW_ + hw;
    float dx = bp[0];
    float dy = bp[HW_];
    float dw = bp[2 * HW_];
    float dh = bp[3 * HW_];
    const float CLIPC = (float)4.135166556742356;  /* log(1000/16) */
    dw = fminf(dw, CLIPC); dh = fminf(dh, CLIPC);
    float w  = x2 - x1 + 1.0f;
    float h  = y2 - y1 + 1.0f;
    float cx = x1 + 0.5f * w;
    float cy = y1 + 0.5f * h;
    float pcx = dx * w + cx;
    float pcy = dy * h + cy;
    float pw = expf(dw) * w;
    float ph = expf(dh) * h;
    float p0 = pcx - 0.5f * pw;
    float p1 = pcy - 0.5f * ph;
    float p2 = pcx + 0.5f * pw - 1.0f;
    float p3 = pcy + 0.5f * ph - 1.0f;
    p0 = fminf(fmaxf(p0, 0.0f), 1023.0f);
    p1 = fminf(fmaxf(p1, 0.0f), 1023.0f);
    p2 = fminf(fmaxf(p2, 0.0f), 1023.0f);
    p3 = fminf(fmaxf(p3, 0.0f), 1023.0f);
    float bw = p2 - p0 + 1.0f;
    float bh = p3 - p1 + 1.0f;
    u32 valid = (bw >= 4.0f && bh >= 4.0f) ? 1u : 0u;
    props[(size_t)job * PRE_ + k]  = make_float4(p0, p1, p2, p3);
    pscore[(size_t)job * PRE_ + k] = score;
    pvalid[(size_t)job * PRE_ + k] = valid;
}

// ---- build NMS suppression bit-matrix, TRANSPOSED [word][row], + diag blocks ----
__global__ __launch_bounds__(64) void k_mask(const float4* __restrict__ props,
                                             u64* __restrict__ maskT,
                                             u64* __restrict__ dmat) {
#pragma clang fp contract(off)
    int x = blockIdx.x, y = blockIdx.y;
    if (x < y) return;                 // lower-triangle words never read
    __shared__ float4 cb[64];
    __shared__ float  ca[64];
    int t = threadIdx.x;
    int job = blockIdx.z;
    int rbase = y * 64;
    int cbase = x * 64;
    int c = cbase + t;
    if (c < PRE_) {
        float4 b = props[(size_t)job * PRE_ + c];
        cb[t] = b;
        ca[t] = (b.z - b.x + 1.0f) * (b.w - b.y + 1.0f);
    }
    __syncthreads();
    int r = rbase + t;
    if (r >= PRE_) return;
    float4 rb = props[(size_t)job * PRE_ + r];
    float ra = (rb.z - rb.x + 1.0f) * (rb.w - rb.y + 1.0f);
    u64 bits = 0;
    int jmax = min(64, PRE_ - cbase);
    for (int j = 0; j < jmax; ++j) {
        int jj = cbase + j;
        if (jj > r) {
            float4 b = cb[j];
            float xx1 = fmaxf(rb.x, b.x);
            float yy1 = fmaxf(rb.y, b.y);
            float xx2 = fminf(rb.z, b.z);
            float yy2 = fminf(rb.w, b.w);
            float iw = fmaxf(xx2 - xx1 + 1.0f, 0.0f);
            float ih = fmaxf(yy2 - yy1 + 1.0f, 0.0f);
            float inter = iw * ih;
            float iou = inter / (ra + ca[j] - inter);
            if (iou > 0.7f) bits |= (1ull << j);
        }
    }
    maskT[((size_t)job * 32 + x) * MROWS_ + r] = bits;   // coalesced across r
    if (x == y) dmat[((size_t)job * 32 + x) * 64 + t] = bits;
}

// ---- greedy scan: column-gather bitset resolve, 1 wave/job ----
// At step w, removed-word w = OR over kept rows so far of maskT[w][row] —
// gathered lane-parallel (one round-trip/step) instead of row-at-a-time.
__global__ __launch_bounds__(64) void k_scan(const u64* __restrict__ maskT,
                                             const u64* __restrict__ dmat,
                                             const u32* __restrict__ pvalid,
                                             const float4* __restrict__ props,
                                             const float* __restrict__ pscore,
                                             float* __restrict__ out) {
    __shared__ u64 keepw[32];
    __shared__ unsigned short K[PRE_];   // kept indices so far (ascending)
    __shared__ int sel[POST_];
    int lane = threadIdx.x;
    int job = blockIdx.x;

    // distributed valid words: lane w (w<32) holds valid bits for boxes [64w,64w+64)
    u64 vreg = 0;
#pragma unroll
    for (int w = 0; w < 32; ++w) {
        int i = w * 64 + lane;
        bool b = (i < PRE_) && (pvalid[(size_t)job * PRE_ + i] != 0);
        u64 bb = __ballot(b);
        if (lane == w) vreg = bb;
    }

    const u64* mcol  = maskT + (size_t)job * 32 * MROWS_;
    const u64* dbase = dmat + (size_t)job * (32 * 64);

    int nk = 0;
    u64 dcur = dbase[lane];            // diag word for block 0, lane t
    for (int w = 0; w < 32; ++w) {
        u64 dnxt = (w < 31) ? dbase[(w + 1) * 64 + lane] : 0;   // prefetch next diag
        // gather word w of all kept rows (independent loads, one wait)
        u64 part = 0;
        const u64* colw = mcol + (size_t)w * MROWS_;
        for (int j = lane; j < nk; j += 64) part |= colw[K[j]];
        // OR-reduce across 64 lanes (butterfly)
#pragma unroll
        for (int m = 1; m < 64; m <<= 1) part |= __shfl_xor(part, m, 64);
        u32 vlo = __builtin_amdgcn_readlane((u32)vreg, w);
        u32 vhi = __builtin_amdgcn_readlane((u32)(vreg >> 32), w);
        u64 lv = (((u64)vhi << 32) | vlo) & ~part;
        // resolve within block via diag words (scalar chain, readlane)
        u32 dlo_all = (u32)dcur, dhi_all = (u32)(dcur >> 32);
        u64 kept = 0;
        while (lv) {
            int i = __builtin_ctzll(lv);
            u32 slo = __builtin_amdgcn_readlane(dlo_all, i);
            u32 shi = __builtin_amdgcn_readlane(dhi_all, i);
            kept |= 1ull << i;
            lv &= ~((((u64)shi << 32) | slo) | (1ull << i));
        }
        if (lane == 0) keepw[w] = kept;
        // append kept indices to K
        bool f = ((kept >> lane) & 1ull) != 0;
        int rank = (int)__popcll(kept & ((1ull << lane) - 1ull));
        if (f) K[nk + rank] = (unsigned short)(w * 64 + lane);
        nk += (int)__popcll(kept);
        dcur = dnxt;
        __syncthreads();               // order K/keepw LDS writes (1 wave: cheap)
    }

    // select first POST_ kept (in order), then fill with unkept (in order)
    int cnt = 0;
    for (int w = 0; w < 32 && cnt < POST_; ++w) {
        u64 kb = keepw[w];
        bool f = ((kb >> lane) & 1ull) != 0;
        int rank = (int)__popcll(kb & ((1ull << lane) - 1ull));
        if (f) { int p = cnt + rank; if (p < POST_) sel[p] = w * 64 + lane; }
        cnt += (int)__popcll(kb);
    }
    if (cnt < POST_) {
        int c2 = cnt;
        for (int w = 0; w < 32 && c2 < POST_; ++w) {
            u64 kb = keepw[w];
            int i = w * 64 + lane;
            bool f = (i < PRE_) && (((kb >> lane) & 1ull) == 0);
            u64 bb = __ballot(f);
            int rank = (int)__popcll(bb & ((1ull << lane) - 1ull));
            if (f) { int p = c2 + rank; if (p < POST_) sel[p] = i | (1 << 30); }
            c2 += (int)__popcll(bb);
        }
    }
    __syncthreads();
    for (int r = lane; r < POST_; r += 64) {
        int e = sel[r];
        int pos = e & 0x3fffffff;
        bool kept = (e & (1 << 30)) == 0;
        float4 bx = props[(size_t)job * PRE_ + pos];
        float sc = kept ? pscore[(size_t)job * PRE_ + pos] : NEG_;
        size_t o = ((size_t)job * POST_ + r) * 5;
        out[o + 0] = bx.x; out[o + 1] = bx.y; out[o + 2] = bx.z; out[o + 3] = bx.w;
        out[o + 4] = sc;
    }
}

extern "C" void kernel_launch(void* const* d_in, const int* in_sizes, int n_in,
                              void* d_out, int out_size, void* d_ws, size_t ws_size,
                              hipStream_t stream) {
    const float* anchL = (const float*)d_in[0];
    const float* anchR = (const float*)d_in[1];
    const float* objL  = (const float*)d_in[2];
    const float* objR  = (const float*)d_in[3];
    const float* bregL = (const float*)d_in[4];
    const float* bregR = (const float*)d_in[5];
    float* out = (float*)d_out;

    char* ws = (char*)d_ws;
    u32* hist    = (u32*)(ws + HIST_OFF);
    u32* candCnt = (u32*)(ws + CNT_OFF);
    u32* tbin    = (u32*)(ws + TBIN_OFF);
    u64* cand    = (u64*)(ws + CAND_OFF);
    u64* topk    = (u64*)(ws + TOPK_OFF);
    float4* props = (float4*)(ws + PROP_OFF);
    float* pscore = (float*)(ws + SCOR_OFF);
    u32* pvalid   = (u32*)(ws + VALD_OFF);
    u64* dmat     = (u64*)(ws + DMAT_OFF);
    u64* maskT    = (u64*)(ws + MASK_OFF);

    // zero hist + padded candCnt (ws is poisoned 0xAA before every call)
    hipMemsetAsync(ws, 0, TBIN_OFF, stream);

    hipLaunchKernelGGL(k_hist,    dim3(16, NJOB_), dim3(256), 0, stream, objL, objR, hist);
    hipLaunchKernelGGL(k_thresh,  dim3(NJOB_),     dim3(256), 0, stream, hist, tbin);
    hipLaunchKernelGGL(k_compact, dim3(64, NJOB_), dim3(256), 0, stream, objL, objR, tbin, candCnt, cand);
    hipLaunchKernelGGL(k_sort,    dim3(NJOB_),     dim3(1024), 0, stream, candCnt, cand, topk);
    hipLaunchKernelGGL(k_decode,  dim3(8, NJOB_),  dim3(256), 0, stream,
                       anchL, anchR, bregL, bregR, topk, props, pscore, pvalid);
    hipLaunchKernelGGL(k_mask,    dim3(32, 32, NJOB_), dim3(64), 0, stream, props, maskT, dmat);
    hipLaunchKernelGGL(k_scan,    dim3(NJOB_),     dim3(64), 0, stream,
                       maskT, dmat, pvalid, props, pscore, out);
}

// Round 8
// 541.937 us; speedup vs baseline: 1.2562x; 1.2562x over previous
//
#include <hip/hip_runtime.h>
#include <cstdint>
#include <cstddef>

typedef unsigned int u32;
typedef unsigned long long u64;

#define A_      15
#define N_      16
#define HW_     16384      /* 128*128 */
#define NUMEL_  245760     /* A_*HW_ */
#define PRE_    2000
#define POST_   1000
#define CAP_    4096
#define NBIN_   8192
#define NJOB_   32
#define MASKW_  32         /* words per mask row */
#define NEG_    (-1000000000.0f)
#define CNTSTRIDE_ 16      /* one 64B line per job counter */

// ---------------- workspace layout (bytes) ----------------
#define HIST_OFF  ((size_t)0)                         /* 32*8192*4 = 1048576 */
#define CNT_OFF   ((size_t)1048576)                   /* 32*16*4 = 2048 (padded) */
#define TBIN_OFF  ((size_t)1050624)                   /* 32*4 -> pad 128 */
#define CAND_OFF  ((size_t)1050752)                   /* 32*4096*8 = 1048576 */
#define TOPK_OFF  ((size_t)2099328)                   /* 32*2048*8 = 524288 */
#define PROP_OFF  ((size_t)2623616)                   /* 32*2000*16 = 1024000 */
#define SCOR_OFF  ((size_t)3647616)                   /* 32*2000*4 = 256000 */
#define VALD_OFF  ((size_t)3903616)                   /* 32*2000*4 = 256000 */
#define DMAT_OFF  ((size_t)4159616)                   /* 32*32*64*8 = 524288 */
#define MASK_OFF  ((size_t)4683904)                   /* 32*2000*32*8 = 16384000 */
/* total ~21.1 MB */

__device__ __forceinline__ float sigmoid_f(float x) {
#pragma clang fp contract(off)
    return 1.0f / (1.0f + expf(-x));
}

// ---- histogram of sigmoid float bits >> 17 (8192 bins), per job ----
__global__ void k_hist(const float* __restrict__ objL, const float* __restrict__ objR,
                       u32* __restrict__ hist) {
    __shared__ u32 h[NBIN_];
    int tid = threadIdx.x;
    for (int b = tid; b < NBIN_; b += 256) h[b] = 0;
    __syncthreads();
    int job = blockIdx.y;
    const float* obj = (job >= 16 ? objR : objL) + (size_t)(job & 15) * NUMEL_;
    int base = blockIdx.x * 15360;
    for (int it = 0; it < 60; ++it) {
        int e = base + it * 256 + tid;
        float s = sigmoid_f(obj[e]);
        u32 bin = __float_as_uint(s) >> 17;   // s in [0,1] -> bin <= 8128
        atomicAdd(&h[bin], 1u);
    }
    __syncthreads();
    u32* gh = hist + (size_t)job * NBIN_;
    for (int b = tid; b < NBIN_; b += 256) {
        u32 c = h[b];
        if (c) atomicAdd(&gh[b], c);
    }
}

// ---- find threshold bin T: smallest-score bin s.t. count(bin >= T) >= PRE_ ----
__global__ void k_thresh(const u32* __restrict__ hist, u32* __restrict__ tbin) {
    __shared__ u32 part[256];
    int job = blockIdx.x, tid = threadIdx.x;
    const u32* gh = hist + (size_t)job * NBIN_;
    u32 sum = 0;
    for (int b = 0; b < 32; ++b) sum += gh[tid * 32 + b];
    part[tid] = sum;
    __syncthreads();
    if (tid == 0) {
        u32 suffix = 0; int T = 0;
        for (int t = 255; t >= 0; --t) {
            if (suffix + part[t] >= PRE_) {
                for (int b = t * 32 + 31; b >= t * 32; --b) {
                    suffix += gh[b];
                    if (suffix >= PRE_) { T = b; break; }
                }
                break;
            }
            suffix += part[t];
        }
        tbin[job] = (u32)T;
    }
}

// ---- compact candidates: block-aggregated reservation (1 global atomic/block) ----
__global__ void k_compact(const float* __restrict__ objL, const float* __restrict__ objR,
                          const u32* __restrict__ tbin, u32* __restrict__ candCnt,
                          u64* __restrict__ cand) {
    __shared__ u32 lrank;
    __shared__ u32 lbase;
    int tid = threadIdx.x;
    int job = blockIdx.y;
    const float* obj = (job >= 16 ? objR : objL) + (size_t)(job & 15) * NUMEL_;
    u32 T = tbin[job];
    int base = blockIdx.x * 3840;
    if (tid == 0) lrank = 0;
    __syncthreads();
    u32 keys[15];
    u32 mymask = 0;
#pragma unroll
    for (int it = 0; it < 15; ++it) {
        int e = base + it * 256 + tid;
        float s = sigmoid_f(obj[e]);
        u32 bits = __float_as_uint(s);
        keys[it] = bits;
        if ((bits >> 17) >= T) mymask |= (1u << it);
    }
    int mycnt = __popc(mymask);
    u32 myoff = 0;
    if (mycnt) myoff = atomicAdd(&lrank, (u32)mycnt);
    __syncthreads();
    if (tid == 0) lbase = atomicAdd(&candCnt[job * CNTSTRIDE_], lrank);
    __syncthreads();
    u32 off = lbase + myoff;
    u64* cj = cand + (size_t)job * CAP_;
#pragma unroll
    for (int it = 0; it < 15; ++it) {
        if (mymask & (1u << it)) {
            int e = base + it * 256 + tid;
            // e = a*HW + hw ; score index i = hw*A + a
            u32 i = (u32)((e & (HW_ - 1)) * A_ + (e >> 14));
            if (off < CAP_) cj[off] = ((u64)keys[it] << 32) | (u64)(~i);
            off++;
        }
    }
}

// ---- per-job bitonic sort (descending) of candidate keys; emit top 2000 ----
__global__ __launch_bounds__(1024) void k_sort(const u32* __restrict__ candCnt,
                                               const u64* __restrict__ cand,
                                               u64* __restrict__ topk) {
    __shared__ u64 a[CAP_];
    int tid = threadIdx.x, job = blockIdx.x;
    u32 cnt = candCnt[job * CNTSTRIDE_]; if (cnt > CAP_) cnt = CAP_;
    const u64* c = cand + (size_t)job * CAP_;
    for (int i = tid; i < CAP_; i += 1024) a[i] = (i < (int)cnt) ? c[i] : 0ull;
    __syncthreads();
    for (int k = 2; k <= CAP_; k <<= 1) {
        for (int j = k >> 1; j > 0; j >>= 1) {
            for (int i = tid; i < CAP_; i += 1024) {
                int ixj = i ^ j;
                if (ixj > i) {
                    u64 x = a[i], y = a[ixj];
                    bool up = (i & k) == 0;
                    if (up ? (x < y) : (x > y)) { a[i] = y; a[ixj] = x; }
                }
            }
            __syncthreads();
        }
    }
    u64* t = topk + (size_t)job * 2048;
    for (int i = tid; i < PRE_; i += 1024) t[i] = a[i];
}

// ---- decode top-2000 boxes, clip, min-size validity ----
__global__ void k_decode(const float* __restrict__ anchL, const float* __restrict__ anchR,
                         const float* __restrict__ bregL, const float* __restrict__ bregR,
                         const u64* __restrict__ topk, float4* __restrict__ props,
                         float* __restrict__ pscore, u32* __restrict__ pvalid) {
#pragma clang fp contract(off)
    int k = blockIdx.x * 256 + threadIdx.x;
    if (k >= PRE_) return;
    int job = blockIdx.y;
    int n = job & 15;
    const float* anch = (job >= 16 ? anchR : anchL);
    const float* breg = (job >= 16 ? bregR : bregL);
    u64 key = topk[(size_t)job * 2048 + k];
    u32 i = ~(u32)key;
    float score = __uint_as_float((u32)(key >> 32));
    int a  = (int)(i % 15u);
    int hw = (int)(i / 15u);
    const float* ap = anch + ((size_t)n * NUMEL_ + i) * 4;
    float x1 = ap[0], y1 = ap[1], x2 = ap[2], y2 = ap[3];
    const float* bp = breg + (size_t)n * (A_ * 4) * HW_ + (size_t)(a * 4) * HW_ + hw;
    float dx = bp[0];
    float dy = bp[HW_];
    float dw = bp[2 * HW_];
    float dh = bp[3 * HW_];
    const float CLIPC = (float)4.135166556742356;  /* log(1000/16) */
    dw = fminf(dw, CLIPC); dh = fminf(dh, CLIPC);
    float w  = x2 - x1 + 1.0f;
    float h  = y2 - y1 + 1.0f;
    float cx = x1 + 0.5f * w;
    float cy = y1 + 0.5f * h;
    float pcx = dx * w + cx;
    float pcy = dy * h + cy;
    float pw = expf(dw) * w;
    float ph = expf(dh) * h;
    float p0 = pcx - 0.5f * pw;
    float p1 = pcy - 0.5f * ph;
    float p2 = pcx + 0.5f * pw - 1.0f;
    float p3 = pcy + 0.5f * ph - 1.0f;
    p0 = fminf(fmaxf(p0, 0.0f), 1023.0f);
    p1 = fminf(fmaxf(p1, 0.0f), 1023.0f);
    p2 = fminf(fmaxf(p2, 0.0f), 1023.0f);
    p3 = fminf(fmaxf(p3, 0.0f), 1023.0f);
    float bw = p2 - p0 + 1.0f;
    float bh = p3 - p1 + 1.0f;
    u32 valid = (bw >= 4.0f && bh >= 4.0f) ? 1u : 0u;
    props[(size_t)job * PRE_ + k]  = make_float4(p0, p1, p2, p3);
    pscore[(size_t)job * PRE_ + k] = score;
    pvalid[(size_t)job * PRE_ + k] = valid;
}

// ---- build NMS suppression bit-matrix (upper triangle only) + diag blocks ----
__global__ __launch_bounds__(64) void k_mask(const float4* __restrict__ props,
                                             u64* __restrict__ mask,
                                             u64* __restrict__ dmat) {
#pragma clang fp contract(off)
    int x = blockIdx.x, y = blockIdx.y;
    if (x < y) return;                 // lower-triangle words never read
    __shared__ float4 cb[64];
    __shared__ float  ca[64];
    int t = threadIdx.x;
    int job = blockIdx.z;
    int rbase = y * 64;
    int cbase = x * 64;
    int c = cbase + t;
    if (c < PRE_) {
        float4 b = props[(size_t)job * PRE_ + c];
        cb[t] = b;
        ca[t] = (b.z - b.x + 1.0f) * (b.w - b.y + 1.0f);
    }
    __syncthreads();
    int r = rbase + t;
    if (r >= PRE_) return;
    float4 rb = props[(size_t)job * PRE_ + r];
    float ra = (rb.z - rb.x + 1.0f) * (rb.w - rb.y + 1.0f);
    u64 bits = 0;
    int jmax = min(64, PRE_ - cbase);
    for (int j = 0; j < jmax; ++j) {
        int jj = cbase + j;
        if (jj > r) {
            float4 b = cb[j];
            float xx1 = fmaxf(rb.x, b.x);
            float yy1 = fmaxf(rb.y, b.y);
            float xx2 = fminf(rb.z, b.z);
            float yy2 = fminf(rb.w, b.w);
            float iw = fmaxf(xx2 - xx1 + 1.0f, 0.0f);
            float ih = fmaxf(yy2 - yy1 + 1.0f, 0.0f);
            float inter = iw * ih;
            float iou = inter / (ra + ca[j] - inter);
            if (iou > 0.7f) bits |= (1ull << j);
        }
    }
    mask[((size_t)job * PRE_ + r) * MASKW_ + x] = bits;
    if (x == y) dmat[((size_t)job * 32 + x) * 64 + t] = bits;
}

// ---- greedy scan, 512 threads/job: multi-wave gather + wave-0 scalar resolve ----
// Step w: phase A (8 waves) ORs kept rows of block w-1 into LDS removed-bitmap
// (coalesced loads, one wait, LDS atomicOr); phase B (wave 0) resolves block w
// via the readlane/ctz diag chain. Two barriers/step.
__global__ __launch_bounds__(512) void k_scan(const u64* __restrict__ mask,
                                              const u64* __restrict__ dmat,
                                              const u32* __restrict__ pvalid,
                                              const float4* __restrict__ props,
                                              const float* __restrict__ pscore,
                                              float* __restrict__ out) {
    __shared__ u64 dlds[32 * 64];      // all diag words, 16 KB
    __shared__ u64 vwords[32];
    __shared__ u64 keepw[32];
    __shared__ u32 remvLo[32];
    __shared__ u32 remvHi[32];
    __shared__ unsigned char Klist[64];
    __shared__ u32 nkeptS;
    __shared__ int sel[POST_];
    int tid  = threadIdx.x;
    int lane = tid & 63;
    int wv   = tid >> 6;
    int job  = blockIdx.x;

    // stage diag blocks to LDS (coalesced)
    const u64* dbase = dmat + (size_t)job * (32 * 64);
    for (int i = tid; i < 32 * 64; i += 512) dlds[i] = dbase[i];
    // valid words via per-wave ballot: rows it*512 + tid -> word it*8 + wv
    for (int it = 0; it < 4; ++it) {
        int i = it * 512 + tid;
        bool b = (i < PRE_) && (pvalid[(size_t)job * PRE_ + i] != 0);
        u64 bb = __ballot(b);
        if (lane == 0) vwords[it * 8 + wv] = bb;
    }
    if (tid < 32) { remvLo[tid] = 0; remvHi[tid] = 0; }
    if (tid == 0) nkeptS = 0;
    __syncthreads();

    const u64* mrow = mask + (size_t)job * PRE_ * MASKW_;

    for (int w = 0; w < 32; ++w) {
        // phase A: OR kept rows of block w-1 into remv (words >= w only; lower
        // words are either already consumed or unwritten)
        if (w > 0) {
            int nk = (int)nkeptS;
            int word = w + (tid & 31);
            int slot0 = tid >> 5;          // 0..15
            if (word < 32 && nk > 0) {
                u64 acc = 0;
                for (int s = slot0; s < nk; s += 16) {
                    int row = (w - 1) * 64 + (int)Klist[s];
                    acc |= mrow[(size_t)row * MASKW_ + word];
                }
                if (acc) {
                    atomicOr(&remvLo[word], (u32)acc);
                    atomicOr(&remvHi[word], (u32)(acc >> 32));
                }
            }
        }
        __syncthreads();
        // phase B: wave 0 resolves block w
        if (wv == 0) {
            u64 rw = (((u64)remvHi[w]) << 32) | (u64)remvLo[w];
            u64 lv = vwords[w] & ~rw;
            u64 dcur = dlds[w * 64 + lane];
            u32 dlo = (u32)dcur, dhi = (u32)(dcur >> 32);
            u64 kept = 0;
            while (lv) {
                int i = __builtin_ctzll(lv);
                u32 slo = __builtin_amdgcn_readlane(dlo, i);
                u32 shi = __builtin_amdgcn_readlane(dhi, i);
                kept |= 1ull << i;
                lv &= ~((((u64)shi << 32) | slo) | (1ull << i));
            }
            if (lane == 0) keepw[w] = kept;
            bool f = ((kept >> lane) & 1ull) != 0;
            int rank = (int)__popcll(kept & ((1ull << lane) - 1ull));
            if (f) Klist[rank] = (unsigned char)lane;
            if (lane == 0) nkeptS = (u32)__popcll(kept);
        }
        __syncthreads();
    }

    // selection (wave 0): first POST_ kept in order, then unkept fill
    if (wv == 0) {
        int cnt = 0;
        for (int w = 0; w < 32 && cnt < POST_; ++w) {
            u64 kb = keepw[w];
            bool f = ((kb >> lane) & 1ull) != 0;
            int rank = (int)__popcll(kb & ((1ull << lane) - 1ull));
            if (f) { int p = cnt + rank; if (p < POST_) sel[p] = w * 64 + lane; }
            cnt += (int)__popcll(kb);
        }
        if (cnt < POST_) {
            int c2 = cnt;
            for (int w = 0; w < 32 && c2 < POST_; ++w) {
                u64 kb = keepw[w];
                int i = w * 64 + lane;
                bool f = (i < PRE_) && (((kb >> lane) & 1ull) == 0);
                u64 bb = __ballot(f);
                int rank = (int)__popcll(bb & ((1ull << lane) - 1ull));
                if (f) { int p = c2 + rank; if (p < POST_) sel[p] = i | (1 << 30); }
                c2 += (int)__popcll(bb);
            }
        }
    }
    __syncthreads();
    for (int r = tid; r < POST_; r += 512) {
        int e = sel[r];
        int pos = e & 0x3fffffff;
        bool kept = (e & (1 << 30)) == 0;
        float4 bx = props[(size_t)job * PRE_ + pos];
        float sc = kept ? pscore[(size_t)job * PRE_ + pos] : NEG_;
        size_t o = ((size_t)job * POST_ + r) * 5;
        out[o + 0] = bx.x; out[o + 1] = bx.y; out[o + 2] = bx.z; out[o + 3] = bx.w;
        out[o + 4] = sc;
    }
}

extern "C" void kernel_launch(void* const* d_in, const int* in_sizes, int n_in,
                              void* d_out, int out_size, void* d_ws, size_t ws_size,
                              hipStream_t stream) {
    const float* anchL = (const float*)d_in[0];
    const float* anchR = (const float*)d_in[1];
    const float* objL  = (const float*)d_in[2];
    const float* objR  = (const float*)d_in[3];
    const float* bregL = (const float*)d_in[4];
    const float* bregR = (const float*)d_in[5];
    float* out = (float*)d_out;

    char* ws = (char*)d_ws;
    u32* hist    = (u32*)(ws + HIST_OFF);
    u32* candCnt = (u32*)(ws + CNT_OFF);
    u32* tbin    = (u32*)(ws + TBIN_OFF);
    u64* cand    = (u64*)(ws + CAND_OFF);
    u64* topk    = (u64*)(ws + TOPK_OFF);
    float4* props = (float4*)(ws + PROP_OFF);
    float* pscore = (float*)(ws + SCOR_OFF);
    u32* pvalid   = (u32*)(ws + VALD_OFF);
    u64* dmat     = (u64*)(ws + DMAT_OFF);
    u64* mask     = (u64*)(ws + MASK_OFF);

    // zero hist + padded candCnt (ws is poisoned 0xAA before every call)
    hipMemsetAsync(ws, 0, TBIN_OFF, stream);

    hipLaunchKernelGGL(k_hist,    dim3(16, NJOB_), dim3(256), 0, stream, objL, objR, hist);
    hipLaunchKernelGGL(k_thresh,  dim3(NJOB_),     dim3(256), 0, stream, hist, tbin);
    hipLaunchKernelGGL(k_compact, dim3(64, NJOB_), dim3(256), 0, stream, objL, objR, tbin, candCnt, cand);
    hipLaunchKernelGGL(k_sort,    dim3(NJOB_),     dim3(1024), 0, stream, candCnt, cand, topk);
    hipLaunchKernelGGL(k_decode,  dim3(8, NJOB_),  dim3(256), 0, stream,
                       anchL, anchR, bregL, bregR, topk, props, pscore, pvalid);
    hipLaunchKernelGGL(k_mask,    dim3(32, 32, NJOB_), dim3(64), 0, stream, props, mask, dmat);
    hipLaunchKernelGGL(k_scan,    dim3(NJOB_),     dim3(512), 0, stream,
                       mask, dmat, pvalid, props, pscore, out);
}